// Round 15
// baseline (761.433 us; speedup 1.0000x reference)
//
#include <hip/hip_runtime.h>
#include <hip/hip_bf16.h>
#include <hip/hip_fp16.h>
#include <hip/hip_cooperative_groups.h>

// GCN 2-layer: N=50000, E=800000, 128->128(relu)->64.
// ONE cooperative mega-kernel, 8 phases + grid.sync between:
//  P0 W-pack + per-chunk histogram (atomic totals)   [memset totals first]
//  P1 scanrow (bucketStart + per-chunk bases)
//  P2 partition edges -> bucket-grouped tmp
//  P3 per-bucket LDS count+scan -> offsets, dinv, csr_src
//  P4 gemm1: h1 = dinv*(x@W1)  (fp16 MFMA, prescaled)
//  P5 agg1:  y = relu(dinv*(self+sum h1[src]) + b1)  (pure-add inner loop)
//  P6 gemm2: h2 = dinv*(y@W2)
//  P7 agg2:  out = dinv*(self+sum h2[src]) + b2
// Phase bodies are the round-11 champion kernels, grid-strided.

#define CHUNK 4096
#define BSHIFT 7
#define BSIZE 128
#define BCAP 4096

typedef unsigned int uint;
typedef _Float16 f16x8 __attribute__((ext_vector_type(8)));
typedef float f32x4 __attribute__((ext_vector_type(4)));

__device__ __forceinline__ float2 h2f(uint v) {
  __half2 h;
  __builtin_memcpy(&h, &v, 4);
  return __half22float2(h);
}

__device__ __forceinline__ uint f2h(float a, float b) {
  __half2 h = __halves2half2(__float2half_rn(a), __float2half_rn(b));
  uint r;
  __builtin_memcpy(&r, &h, 4);
  return r;
}

struct MegaArgs {
  const float* x;
  const int* ei;
  const float* W1;
  const float* b1;
  const float* W2;
  const float* b2;
  float* out;
  int* gh;
  int* totals;
  int* bstart;
  int* gbase;
  int* tmp;
  int* offsets;
  float* dinv;
  int* csr;
  _Float16* pW;
  _Float16* h1;
  _Float16* y;
  _Float16* h2;
  int N, E, nbuck, nchunk, GB, AB, G;
};

__global__ __launch_bounds__(256, 6) void mega_k(MegaArgs a) {
  namespace cg = cooperative_groups;
  cg::grid_group grid = cg::this_grid();
  __shared__ int smem[4624];  // 18.5 KB: ebuf|cnt|st|lofs (bucket); reused by hist/scan/part
  __shared__ int s_is64;
  const int tid = threadIdx.x;
  const int bid = blockIdx.x;
  const int G = a.G;

  // int64-vs-int32 edge detection (once per block)
  if (tid < 64) {
    unsigned long long m = __ballot(a.ei[2 * tid + 1] != 0);
    if (tid == 0) s_is64 = (m == 0ULL) ? 1 : 0;
  }
  __syncthreads();
  const int is64 = s_is64;

  // ---------------- P0: W-pack (96 items) + hist (nchunk items) ----------------
  for (int it = bid; it < 96 + a.nchunk; it += G) {
    if (it < 96) {
      int li = it * 256 + tid;
      if (li < 24576) {
        const float* W;
        _Float16* dst;
        int NC, idx;
        if (li < 16384) { W = a.W1; dst = a.pW;         NC = 128; idx = li; }
        else            { W = a.W2; dst = a.pW + 16384; NC = 64;  idx = li - 16384; }
        int NF = NC >> 4;
        int j = idx & 7;
        int l = (idx >> 3) & 63;
        int rest = idx >> 9;
        int c = rest % NF;
        int t = rest / NF;
        int k = t * 32 + ((l >> 4) << 3) + j;
        int col = c * 16 + (l & 15);
        dst[idx] = (_Float16)W[(size_t)k * NC + col];
      }
    } else {
      int c = it - 96;
      for (int i = tid; i < 512; i += 256) smem[i] = 0;
      __syncthreads();
      int base = c * CHUNK;
      int lim = min(CHUNK, a.E - base);
      for (int i = tid; i < lim; i += 256) {
        int e = base + i;
        int d = is64 ? a.ei[2 * ((size_t)a.E + e)] : a.ei[(size_t)a.E + e];
        atomicAdd(&smem[d >> BSHIFT], 1);
      }
      __syncthreads();
      for (int k = tid; k < a.nbuck; k += 256) {
        a.gh[k * a.nchunk + c] = smem[k];
        atomicAdd(&a.totals[k], smem[k]);
      }
      __syncthreads();
    }
  }
  grid.sync();

  // ---------------- P1: scanrow (nbuck items) ----------------
  for (int it = bid; it < a.nbuck; it += G) {
    int* st = smem;
    int k = it;
    int partial = 0;
    for (int i = tid; i < k; i += 256) partial += a.totals[i];
    st[tid] = partial;
    __syncthreads();
    for (int o = 128; o > 0; o >>= 1) {
      if (tid < o) st[tid] += st[tid + o];
      __syncthreads();
    }
    int bs = st[0];
    if (tid == 0) {
      a.bstart[k] = bs;
      if (k == a.nbuck - 1) { a.bstart[a.nbuck] = a.E; a.offsets[a.N] = a.E; }
    }
    __syncthreads();
    int x = (tid < a.nchunk) ? a.gh[k * a.nchunk + tid] : 0;
    st[tid] = x;
    __syncthreads();
    int incl = x;
    for (int o = 1; o < 256; o <<= 1) {
      int add = (tid >= o) ? st[tid - o] : 0;
      __syncthreads();
      incl += add;
      st[tid] = incl;
      __syncthreads();
    }
    if (tid < a.nchunk) a.gbase[k * a.nchunk + tid] = bs + (incl - x);
    __syncthreads();
  }
  grid.sync();

  // ---------------- P2: partition (nchunk items) ----------------
  for (int it = bid; it < a.nchunk; it += G) {
    int c = it;
    int* cur = smem;
    for (int i = tid; i < a.nbuck; i += 256) cur[i] = a.gbase[i * a.nchunk + c];
    __syncthreads();
    int base = c * CHUNK;
    int lim = min(CHUNK, a.E - base);
    for (int i = tid; i < lim; i += 256) {
      int e = base + i;
      int s, d;
      if (is64) {
        s = a.ei[2 * (size_t)e];
        d = a.ei[2 * ((size_t)a.E + e)];
      } else {
        s = a.ei[e];
        d = a.ei[(size_t)a.E + e];
      }
      int p = atomicAdd(&cur[d >> BSHIFT], 1);
      a.tmp[p] = s | ((d & (BSIZE - 1)) << 16);
    }
    __syncthreads();
  }
  grid.sync();

  // ---------------- P3: bucket (nbuck items) ----------------
  for (int it = bid; it < a.nbuck; it += G) {
    int k = it;
    int* ebuf = smem;
    int* cnt  = smem + 4096;
    int* st   = smem + 4224;
    int* lofs = smem + 4480;
    int b0 = a.bstart[k], b1e = a.bstart[k + 1];
    int sz = b1e - b0;
    if (tid < BSIZE) cnt[tid] = 0;
    __syncthreads();
    bool inlds = (sz <= BCAP);
    if (inlds) {
      for (int i = tid; i < sz; i += 256) {
        int v = a.tmp[b0 + i];
        ebuf[i] = v;
        atomicAdd(&cnt[v >> 16], 1);
      }
    } else {
      for (int i = tid; i < sz; i += 256) atomicAdd(&cnt[a.tmp[b0 + i] >> 16], 1);
    }
    __syncthreads();
    int x = (tid < BSIZE) ? cnt[tid] : 0;
    st[tid] = x;
    __syncthreads();
    int incl = x;
    for (int o = 1; o < 256; o <<= 1) {
      int add = (tid >= o) ? st[tid - o] : 0;
      __syncthreads();
      incl += add;
      st[tid] = incl;
      __syncthreads();
    }
    int node = (k << BSHIFT) + tid;
    if (tid < BSIZE) {
      lofs[tid] = incl - x;
      if (node < a.N) {
        a.offsets[node] = b0 + lofs[tid];
        a.dinv[node] = rsqrtf((float)(x + 1));  // +1 self-loop
      }
    }
    __syncthreads();
    if (tid < BSIZE) cnt[tid] = lofs[tid];  // cursor
    __syncthreads();
    if (inlds) {
      for (int i = tid; i < sz; i += 256) {
        int v = ebuf[i];
        int p = atomicAdd(&cnt[v >> 16], 1);
        a.csr[b0 + p] = v & 0xFFFF;
      }
    } else {
      for (int i = tid; i < sz; i += 256) {
        int v = a.tmp[b0 + i];
        int p = atomicAdd(&cnt[v >> 16], 1);
        a.csr[b0 + p] = v & 0xFFFF;
      }
    }
    __syncthreads();
  }
  grid.sync();

  // ---------------- P4: gemm1  h1 = dinv*(x @ W1), fp16 ----------------
  {
    int lane = tid & 63;
    int w = tid >> 6;
    const uint4* wp = (const uint4*)a.pW;
    for (int it = bid; it < a.GB; it += G) {
      int row0 = it * 64 + w * 16;
      int arow = row0 + (lane & 15);
      bool av = arow < a.N;
      f32x4 acc[8];
#pragma unroll
      for (int c = 0; c < 8; ++c) acc[c] = (f32x4){0.f, 0.f, 0.f, 0.f};
#pragma unroll
      for (int t = 0; t < 4; ++t) {
        const float* xr = a.x + (size_t)arow * 128 + ((lane >> 4) << 3) + t * 32;
        float4 lo = av ? *(const float4*)xr : make_float4(0.f, 0.f, 0.f, 0.f);
        float4 hi = av ? *(const float4*)(xr + 4) : make_float4(0.f, 0.f, 0.f, 0.f);
        f16x8 afr;
        afr[0] = (_Float16)lo.x; afr[1] = (_Float16)lo.y;
        afr[2] = (_Float16)lo.z; afr[3] = (_Float16)lo.w;
        afr[4] = (_Float16)hi.x; afr[5] = (_Float16)hi.y;
        afr[6] = (_Float16)hi.z; afr[7] = (_Float16)hi.w;
#pragma unroll
        for (int c = 0; c < 8; ++c) {
          uint4 braw = wp[(t * 8 + c) * 64 + lane];
          f16x8 bfr;
          __builtin_memcpy(&bfr, &braw, 16);
          acc[c] = __builtin_amdgcn_mfma_f32_16x16x32_f16(afr, bfr, acc[c], 0, 0, 0);
        }
      }
      int rbase = row0 + ((lane >> 4) << 2);
#pragma unroll
      for (int r = 0; r < 4; ++r) {
        int row = rbase + r;
        if (row < a.N) {
          float di = a.dinv[row];
#pragma unroll
          for (int c = 0; c < 8; ++c)
            a.h1[(size_t)row * 128 + c * 16 + (lane & 15)] = (_Float16)(di * acc[c][r]);
        }
      }
    }
  }
  grid.sync();

  // ---------------- P5: agg1  y = relu(dinv*(self+sum) + b1), fp16 ----------------
  {
    const uint2* hp = (const uint2*)a.h1;
    uint2* yp = (uint2*)a.y;
    int wv = tid >> 6;
    int lane = tid & 63;
    int half = lane >> 5;
    int fl = lane & 31;
    for (int it = bid; it < a.AB; it += G) {
      int node = it * 8 + wv * 2 + half;
      if (node < a.N) {
        int beg = a.offsets[node], end = a.offsets[node + 1];
        int deg = end - beg;
        uint2 su = hp[(size_t)node * 32 + fl];
        float2 sl = h2f(su.x), sh = h2f(su.y);
        float a0 = sl.x, a1 = sl.y, a2 = sh.x, a3 = sh.y;
        int sv = 0;
        if (fl < deg) sv = a.csr[beg + fl];
        int lim = deg < 32 ? deg : 32;
        int e = 0;
        for (; e + 8 <= lim; e += 8) {
          int sA = __shfl(sv, e + 0, 32), sB = __shfl(sv, e + 1, 32);
          int sC = __shfl(sv, e + 2, 32), sD = __shfl(sv, e + 3, 32);
          int sE = __shfl(sv, e + 4, 32), sF = __shfl(sv, e + 5, 32);
          int sG = __shfl(sv, e + 6, 32), sH = __shfl(sv, e + 7, 32);
          uint2 uA = hp[(size_t)sA * 32 + fl];
          uint2 uB = hp[(size_t)sB * 32 + fl];
          uint2 uC = hp[(size_t)sC * 32 + fl];
          uint2 uD = hp[(size_t)sD * 32 + fl];
          uint2 uE = hp[(size_t)sE * 32 + fl];
          uint2 uF = hp[(size_t)sF * 32 + fl];
          uint2 uG = hp[(size_t)sG * 32 + fl];
          uint2 uH = hp[(size_t)sH * 32 + fl];
          float2 lA = h2f(uA.x), hA = h2f(uA.y), lB = h2f(uB.x), hB = h2f(uB.y);
          float2 lC = h2f(uC.x), hC = h2f(uC.y), lD = h2f(uD.x), hD = h2f(uD.y);
          float2 lE = h2f(uE.x), hE = h2f(uE.y), lF = h2f(uF.x), hF = h2f(uF.y);
          float2 lG = h2f(uG.x), hG = h2f(uG.y), lH = h2f(uH.x), hH = h2f(uH.y);
          a0 += ((lA.x + lB.x) + (lC.x + lD.x)) + ((lE.x + lF.x) + (lG.x + lH.x));
          a1 += ((lA.y + lB.y) + (lC.y + lD.y)) + ((lE.y + lF.y) + (lG.y + lH.y));
          a2 += ((hA.x + hB.x) + (hC.x + hD.x)) + ((hE.x + hF.x) + (hG.x + hH.x));
          a3 += ((hA.y + hB.y) + (hC.y + hD.y)) + ((hE.y + hF.y) + (hG.y + hH.y));
        }
        for (; e < lim; ++e) {
          int s = __shfl(sv, e, 32);
          uint2 u = hp[(size_t)s * 32 + fl];
          float2 l = h2f(u.x), h = h2f(u.y);
          a0 += l.x; a1 += l.y; a2 += h.x; a3 += h.y;
        }
        for (int ee = beg + 32; ee < end; ++ee) {  // deg>32 fallback (rare)
          uint2 u = hp[(size_t)a.csr[ee] * 32 + fl];
          float2 l = h2f(u.x), h = h2f(u.y);
          a0 += l.x; a1 += l.y; a2 += h.x; a3 += h.y;
        }
        float di = a.dinv[node];
        float4 bb = *(const float4*)(a.b1 + 4 * fl);
        float o0 = fmaxf(fmaf(di, a0, bb.x), 0.f);
        float o1 = fmaxf(fmaf(di, a1, bb.y), 0.f);
        float o2 = fmaxf(fmaf(di, a2, bb.z), 0.f);
        float o3 = fmaxf(fmaf(di, a3, bb.w), 0.f);
        uint2 o;
        o.x = f2h(o0, o1);
        o.y = f2h(o2, o3);
        yp[(size_t)node * 32 + fl] = o;
      }
    }
  }
  grid.sync();

  // ---------------- P6: gemm2  h2 = dinv*(y @ W2), fp16 ----------------
  {
    int lane = tid & 63;
    int w = tid >> 6;
    const uint4* wp = (const uint4*)(a.pW + 16384);
    for (int it = bid; it < a.GB; it += G) {
      int row0 = it * 64 + w * 16;
      int arow = row0 + (lane & 15);
      bool av = arow < a.N;
      f32x4 acc[4];
#pragma unroll
      for (int c = 0; c < 4; ++c) acc[c] = (f32x4){0.f, 0.f, 0.f, 0.f};
#pragma unroll
      for (int t = 0; t < 4; ++t) {
        const _Float16* yr = a.y + (size_t)arow * 128 + ((lane >> 4) << 3) + t * 32;
        uint4 araw = av ? *(const uint4*)yr : make_uint4(0u, 0u, 0u, 0u);
        f16x8 afr;
        __builtin_memcpy(&afr, &araw, 16);
#pragma unroll
        for (int c = 0; c < 4; ++c) {
          uint4 braw = wp[(t * 4 + c) * 64 + lane];
          f16x8 bfr;
          __builtin_memcpy(&bfr, &braw, 16);
          acc[c] = __builtin_amdgcn_mfma_f32_16x16x32_f16(afr, bfr, acc[c], 0, 0, 0);
        }
      }
      int rbase = row0 + ((lane >> 4) << 2);
#pragma unroll
      for (int r = 0; r < 4; ++r) {
        int row = rbase + r;
        if (row < a.N) {
          float di = a.dinv[row];
#pragma unroll
          for (int c = 0; c < 4; ++c)
            a.h2[(size_t)row * 64 + c * 16 + (lane & 15)] = (_Float16)(di * acc[c][r]);
        }
      }
    }
  }
  grid.sync();

  // ---------------- P7: agg2  out = dinv*(self+sum) + b2, f32 ----------------
  {
    const uint* hp = (const uint*)a.h2;
    int wv = tid >> 6;
    int lane = tid & 63;
    int half = lane >> 5;
    int fl = lane & 31;
    for (int it = bid; it < a.AB; it += G) {
      int node = it * 8 + wv * 2 + half;
      if (node < a.N) {
        int beg = a.offsets[node], end = a.offsets[node + 1];
        int deg = end - beg;
        float2 self = h2f(hp[(size_t)node * 32 + fl]);
        float ax = self.x, ay = self.y;
        int sv = 0;
        if (fl < deg) sv = a.csr[beg + fl];
        int lim = deg < 32 ? deg : 32;
        int e = 0;
        for (; e + 8 <= lim; e += 8) {
          int s0 = __shfl(sv, e + 0, 32), s1 = __shfl(sv, e + 1, 32);
          int s2 = __shfl(sv, e + 2, 32), s3 = __shfl(sv, e + 3, 32);
          int s4 = __shfl(sv, e + 4, 32), s5 = __shfl(sv, e + 5, 32);
          int s6 = __shfl(sv, e + 6, 32), s7 = __shfl(sv, e + 7, 32);
          uint u0 = hp[(size_t)s0 * 32 + fl];
          uint u1 = hp[(size_t)s1 * 32 + fl];
          uint u2 = hp[(size_t)s2 * 32 + fl];
          uint u3 = hp[(size_t)s3 * 32 + fl];
          uint u4 = hp[(size_t)s4 * 32 + fl];
          uint u5 = hp[(size_t)s5 * 32 + fl];
          uint u6 = hp[(size_t)s6 * 32 + fl];
          uint u7 = hp[(size_t)s7 * 32 + fl];
          float2 v0 = h2f(u0), v1 = h2f(u1), v2 = h2f(u2), v3 = h2f(u3);
          float2 v4 = h2f(u4), v5 = h2f(u5), v6 = h2f(u6), v7 = h2f(u7);
          ax += ((v0.x + v1.x) + (v2.x + v3.x)) + ((v4.x + v5.x) + (v6.x + v7.x));
          ay += ((v0.y + v1.y) + (v2.y + v3.y)) + ((v4.y + v5.y) + (v6.y + v7.y));
        }
        for (; e < lim; ++e) {
          int s = __shfl(sv, e, 32);
          float2 v = h2f(hp[(size_t)s * 32 + fl]);
          ax += v.x;
          ay += v.y;
        }
        for (int ee = beg + 32; ee < end; ++ee) {
          float2 v = h2f(hp[(size_t)a.csr[ee] * 32 + fl]);
          ax += v.x;
          ay += v.y;
        }
        float di = a.dinv[node];
        float2 bb = ((const float2*)a.b2)[fl];
        float2 o;
        o.x = fmaf(di, ax, bb.x);
        o.y = fmaf(di, ay, bb.y);
        ((float2*)a.out)[(size_t)node * 32 + fl] = o;
      }
    }
  }
}

extern "C" void kernel_launch(void* const* d_in, const int* in_sizes, int n_in,
                              void* d_out, int out_size, void* d_ws, size_t ws_size,
                              hipStream_t stream) {
  const float* x  = (const float*)d_in[0];
  const int*   ei = (const int*)d_in[1];
  const float* W1 = (const float*)d_in[2];
  const float* b1 = (const float*)d_in[3];
  const float* W2 = (const float*)d_in[4];
  const float* b2 = (const float*)d_in[5];
  float* out = (float*)d_out;

  const int N = in_sizes[0] / 128;   // 50000
  const int E = in_sizes[1] / 2;     // 800000
  const int NBUCK = (N + BSIZE - 1) >> BSHIFT;   // 391
  const int NCHUNK = (E + CHUNK - 1) / CHUNK;    // 196

  char* w = (char*)d_ws;
  size_t off = 0;
  auto alloc = [&](size_t bytes) -> void* {
    void* p = w + off;
    off = (off + bytes + 511) & ~(size_t)511;
    return p;
  };
  int*       gh      = (int*)alloc((size_t)NBUCK * NCHUNK * 4);
  int*       gbase   = (int*)alloc((size_t)NBUCK * NCHUNK * 4);
  int*       totals  = (int*)alloc((size_t)NBUCK * 4);
  int*       bstart  = (int*)alloc((size_t)(NBUCK + 1) * 4);
  int*       tmp     = (int*)alloc((size_t)E * 4);
  int*       offsets = (int*)alloc((size_t)(N + 1) * 4);
  float*     dinv    = (float*)alloc((size_t)N * 4);
  int*       csr     = (int*)alloc((size_t)E * 4);
  _Float16*  pW      = (_Float16*)alloc(24576 * 2);
  _Float16*  h1      = (_Float16*)alloc((size_t)N * 128 * 2);  // dinv-prescaled
  _Float16*  y       = (_Float16*)alloc((size_t)N * 128 * 2);
  _Float16*  h2      = (_Float16*)alloc((size_t)N * 64 * 2);   // dinv-prescaled

  // co-residency sizing for the cooperative launch
  int nb = 0;
  if (hipOccupancyMaxActiveBlocksPerMultiprocessor(&nb, mega_k, 256, 0) != hipSuccess || nb < 1)
    nb = 4;
  if (nb > 8) nb = 8;
  int G = nb * 256;  // 256 CUs on MI355X
  if (G > 2048) G = 2048;

  MegaArgs a;
  a.x = x; a.ei = ei; a.W1 = W1; a.b1 = b1; a.W2 = W2; a.b2 = b2; a.out = out;
  a.gh = gh; a.totals = totals; a.bstart = bstart; a.gbase = gbase; a.tmp = tmp;
  a.offsets = offsets; a.dinv = dinv; a.csr = csr; a.pW = pW;
  a.h1 = h1; a.y = y; a.h2 = h2;
  a.N = N; a.E = E; a.nbuck = NBUCK; a.nchunk = NCHUNK;
  a.GB = (N + 63) / 64; a.AB = (N + 7) / 8; a.G = G;

  hipMemsetAsync(totals, 0, (size_t)NBUCK * 4, stream);
  void* kargs[] = { (void*)&a };
  hipLaunchCooperativeKernel(mega_k, dim3(G), dim3(256), kargs, 0, stream);
}

// Round 16
// 113.711 us; speedup vs baseline: 6.6962x; 6.6962x over previous
//
#include <hip/hip_runtime.h>
#include <hip/hip_bf16.h>
#include <hip/hip_fp16.h>

// GCN 2-layer: N=50000 nodes, E=800000 edges, 128->128(relu)->64.
// Round-11 champion structure + atomic-totals (tot_k eliminated).
// CSR build: two-level LDS-binned partition (128-node buckets, no global
// scatter atomics). GEMMs: fp16 MFMA 16x16x32, LDS-free, prepacked W,
// dinv-prescaled outputs. Aggs: 32-lane segment per node, pure-add inner
// loop (8 gathers in flight), width-32 shuffles, f32 accumulation.

#define CHUNK 4096   // edges per partition chunk
#define BSHIFT 7
#define BSIZE 128    // nodes per bucket
#define BCAP 4096    // max edges per bucket held in LDS (avg ~2046)

typedef unsigned int uint;
typedef _Float16 f16x8 __attribute__((ext_vector_type(8)));
typedef float f32x4 __attribute__((ext_vector_type(4)));

__device__ __forceinline__ float2 h2f(uint v) {
  __half2 h;
  __builtin_memcpy(&h, &v, 4);
  return __half22float2(h);
}

__device__ __forceinline__ uint f2h(float a, float b) {
  __half2 h = __halves2half2(__float2half_rn(a), __float2half_rn(b));
  uint r;
  __builtin_memcpy(&r, &h, 4);
  return r;
}

// int64-vs-int32 detection per block: wave-0 ballot over first 64 high words.
__device__ __forceinline__ int block_is64(const int* ei, int* s_is64) {
  if (threadIdx.x < 64) {
    unsigned long long m = __ballot(ei[2 * threadIdx.x + 1] != 0);
    if (threadIdx.x == 0) *s_is64 = (m == 0ULL) ? 1 : 0;
  }
  __syncthreads();
  return *s_is64;
}

// A1 (+fused W-prep): blocks < nchunk: per-chunk histogram over buckets
// (dst>>BSHIFT) + atomicAdd into totals; blocks >= nchunk: pack W1/W2 into
// fragment-linear fp16. totals must be zeroed before this launch.
__global__ __launch_bounds__(256) void hist_prep_k(const int* __restrict__ ei,
                                                   int* __restrict__ gh,
                                                   int* __restrict__ totals,
                                                   const float* __restrict__ W1,
                                                   const float* __restrict__ W2,
                                                   _Float16* __restrict__ P,
                                                   int E, int nchunk, int nbuck) {
  if (blockIdx.x >= nchunk) {
    int li = (blockIdx.x - nchunk) * 256 + threadIdx.x;  // 0..24575
    if (li >= 24576) return;
    const float* W;
    _Float16* dst;
    int NC, idx;
    if (li < 16384) { W = W1; dst = P;         NC = 128; idx = li; }
    else            { W = W2; dst = P + 16384; NC = 64;  idx = li - 16384; }
    int NF = NC >> 4;
    int j = idx & 7;
    int l = (idx >> 3) & 63;
    int rest = idx >> 9;
    int c = rest % NF;
    int t = rest / NF;
    int k = t * 32 + ((l >> 4) << 3) + j;
    int col = c * 16 + (l & 15);
    dst[idx] = (_Float16)W[(size_t)k * NC + col];
    return;
  }
  __shared__ int h[512];
  __shared__ int s_is64;
  int c = blockIdx.x;
  for (int i = threadIdx.x; i < 512; i += 256) h[i] = 0;
  int is64 = block_is64(ei, &s_is64);  // includes __syncthreads
  int base = c * CHUNK;
  int lim = min(CHUNK, E - base);
  for (int i = threadIdx.x; i < lim; i += 256) {
    int e = base + i;
    int d = is64 ? ei[2 * ((size_t)E + e)] : ei[(size_t)E + e];
    atomicAdd(&h[d >> BSHIFT], 1);
  }
  __syncthreads();
  for (int k = threadIdx.x; k < nbuck; k += 256) {
    gh[k * nchunk + c] = h[k];
    atomicAdd(&totals[k], h[k]);
  }
}

// A2: block k: bucketStart[k] (= sum totals[<k]) + scan of gh row k -> gbase.
__global__ __launch_bounds__(256) void scanrow_k(const int* __restrict__ gh,
                                                 const int* __restrict__ totals,
                                                 int* __restrict__ gbase,
                                                 int* __restrict__ bucketStart,
                                                 int* __restrict__ offsets,
                                                 int nchunk, int nbuck, int N, int E) {
  __shared__ int st[256];
  int k = blockIdx.x;
  int t = threadIdx.x;
  int partial = 0;
  for (int i = t; i < k; i += 256) partial += totals[i];
  st[t] = partial;
  __syncthreads();
  for (int o = 128; o > 0; o >>= 1) {
    if (t < o) st[t] += st[t + o];
    __syncthreads();
  }
  int bs = st[0];
  if (t == 0) {
    bucketStart[k] = bs;
    if (k == nbuck - 1) { bucketStart[nbuck] = E; offsets[N] = E; }
  }
  __syncthreads();
  int x = (t < nchunk) ? gh[k * nchunk + t] : 0;
  st[t] = x;
  __syncthreads();
  int incl = x;
  for (int o = 1; o < 256; o <<= 1) {
    int add = (t >= o) ? st[t - o] : 0;
    __syncthreads();
    incl += add;
    st[t] = incl;
    __syncthreads();
  }
  if (t < nchunk) gbase[k * nchunk + t] = bs + (incl - x);
}

// A3: partition edges into bucket-grouped tmp, packed (src16 | dstlow7<<16)
__global__ __launch_bounds__(256) void part_k(const int* __restrict__ ei,
                                              const int* __restrict__ gbase,
                                              int* __restrict__ tmp,
                                              int E, int nchunk, int nbuck) {
  __shared__ int cur[512];
  __shared__ int s_is64;
  int c = blockIdx.x;
  for (int i = threadIdx.x; i < nbuck; i += 256) cur[i] = gbase[i * nchunk + c];
  int is64 = block_is64(ei, &s_is64);
  int base = c * CHUNK;
  int lim = min(CHUNK, E - base);
  for (int i = threadIdx.x; i < lim; i += 256) {
    int e = base + i;
    int s, d;
    if (is64) {
      s = ei[2 * (size_t)e];
      d = ei[2 * ((size_t)E + e)];
    } else {
      s = ei[e];
      d = ei[(size_t)E + e];
    }
    int p = atomicAdd(&cur[d >> BSHIFT], 1);
    tmp[p] = s | ((d & (BSIZE - 1)) << 16);
  }
}

// B: one block per 128-node bucket: LDS count+scan -> offsets, dinv, csr_src
__global__ __launch_bounds__(256) void bucket_k(const int* __restrict__ tmp,
                                                const int* __restrict__ bucketStart,
                                                int* __restrict__ csr_src,
                                                int* __restrict__ offsets,
                                                float* __restrict__ dinv,
                                                int N) {
  __shared__ int ebuf[BCAP];
  __shared__ int cnt[BSIZE];
  __shared__ int st[256];
  __shared__ int lofs[BSIZE];
  int k = blockIdx.x;
  int b0 = bucketStart[k], b1 = bucketStart[k + 1];
  int sz = b1 - b0;
  int t = threadIdx.x;
  if (t < BSIZE) cnt[t] = 0;
  __syncthreads();
  bool inlds = (sz <= BCAP);
  if (inlds) {
    for (int i = t; i < sz; i += 256) {
      int v = tmp[b0 + i];
      ebuf[i] = v;
      atomicAdd(&cnt[v >> 16], 1);
    }
  } else {
    for (int i = t; i < sz; i += 256) atomicAdd(&cnt[tmp[b0 + i] >> 16], 1);
  }
  __syncthreads();
  int x = (t < BSIZE) ? cnt[t] : 0;
  st[t] = x;
  __syncthreads();
  int incl = x;
  for (int o = 1; o < 256; o <<= 1) {
    int add = (t >= o) ? st[t - o] : 0;
    __syncthreads();
    incl += add;
    st[t] = incl;
    __syncthreads();
  }
  int node = (k << BSHIFT) + t;
  if (t < BSIZE) {
    lofs[t] = incl - x;
    if (node < N) {
      offsets[node] = b0 + lofs[t];
      dinv[node] = rsqrtf((float)(x + 1));  // +1 self-loop
    }
  }
  __syncthreads();
  if (t < BSIZE) cnt[t] = lofs[t];  // reuse as cursor
  __syncthreads();
  if (inlds) {
    for (int i = t; i < sz; i += 256) {
      int v = ebuf[i];
      int p = atomicAdd(&cnt[v >> 16], 1);
      csr_src[b0 + p] = v & 0xFFFF;
    }
  } else {
    for (int i = t; i < sz; i += 256) {
      int v = tmp[b0 + i];
      int p = atomicAdd(&cnt[v >> 16], 1);
      csr_src[b0 + p] = v & 0xFFFF;
    }
  }
}

// ---- MFMA GEMM: H(fp16 row-major) = dinv[row] * (X[M,128] @ W[128,NC]) ----
// 4 waves/block, wave w: rows blk*64 + w*16. No LDS.
template <int NC, bool A16>
__global__ __launch_bounds__(256) void mfma_gemm_k(const void* __restrict__ Xv,
                                                   const _Float16* __restrict__ Wp,
                                                   const float* __restrict__ dinv,
                                                   _Float16* __restrict__ H, int M) {
  constexpr int NF = NC / 16;
  int lane = threadIdx.x & 63;
  int w = threadIdx.x >> 6;
  int row0 = blockIdx.x * 64 + w * 16;
  int arow = row0 + (lane & 15);
  bool av = arow < M;
  const uint4* wp = (const uint4*)Wp;

  f32x4 acc[NF];
#pragma unroll
  for (int c = 0; c < NF; ++c) acc[c] = (f32x4){0.f, 0.f, 0.f, 0.f};

#pragma unroll
  for (int t = 0; t < 4; ++t) {
    f16x8 a;
    if constexpr (A16) {
      const _Float16* xr = (const _Float16*)Xv + (size_t)arow * 128 + ((lane >> 4) << 3);
      uint4 araw = av ? *(const uint4*)(xr + t * 32) : make_uint4(0u, 0u, 0u, 0u);
      __builtin_memcpy(&a, &araw, 16);
    } else {
      const float* xr = (const float*)Xv + (size_t)arow * 128 + ((lane >> 4) << 3);
      float4 lo = av ? *(const float4*)(xr + t * 32) : make_float4(0.f, 0.f, 0.f, 0.f);
      float4 hi = av ? *(const float4*)(xr + t * 32 + 4) : make_float4(0.f, 0.f, 0.f, 0.f);
      a[0] = (_Float16)lo.x; a[1] = (_Float16)lo.y;
      a[2] = (_Float16)lo.z; a[3] = (_Float16)lo.w;
      a[4] = (_Float16)hi.x; a[5] = (_Float16)hi.y;
      a[6] = (_Float16)hi.z; a[7] = (_Float16)hi.w;
    }
#pragma unroll
    for (int c = 0; c < NF; ++c) {
      uint4 braw = wp[(t * NF + c) * 64 + lane];
      f16x8 b;
      __builtin_memcpy(&b, &braw, 16);
      acc[c] = __builtin_amdgcn_mfma_f32_16x16x32_f16(a, b, acc[c], 0, 0, 0);
    }
  }

  int rbase = row0 + ((lane >> 4) << 2);
#pragma unroll
  for (int r = 0; r < 4; ++r) {
    int row = rbase + r;
    if (row < M) {
      float di = dinv[row];
#pragma unroll
      for (int c = 0; c < NF; ++c)
        H[(size_t)row * NC + c * 16 + (lane & 15)] = (_Float16)(di * acc[c][r]);
    }
  }
}

// ---- agg1: y[i](fp16) = relu( dinv_i*(h'_i + sum_src h'_src) + b1 ), 128 f ----
// h' rows: 32 uint2 (fp16x4) = 256B, dinv-prescaled. One 32-lane SEGMENT per
// node (2/wave): trip counts segment-uniform; shuffles width-32.
__global__ __launch_bounds__(256) void agg1_k(const uint2* __restrict__ hp,
                                              const float* __restrict__ dinv,
                                              const int* __restrict__ offsets,
                                              const int* __restrict__ csr_src,
                                              const float* __restrict__ b,
                                              uint2* __restrict__ y, int n) {
  int wv = threadIdx.x >> 6;
  int lane = threadIdx.x & 63;
  int half = lane >> 5;
  int fl = lane & 31;
  int node = blockIdx.x * 8 + wv * 2 + half;
  if (node >= n) return;  // uniform within segment
  int beg = offsets[node], end = offsets[node + 1];
  int deg = end - beg;
  uint2 su = hp[(size_t)node * 32 + fl];
  float2 sl = h2f(su.x), sh = h2f(su.y);
  float a0 = sl.x, a1 = sl.y, a2 = sh.x, a3 = sh.y;
  int sv = 0;
  if (fl < deg) sv = csr_src[beg + fl];
  int lim = deg < 32 ? deg : 32;
  int e = 0;
  for (; e + 8 <= lim; e += 8) {
    int sA = __shfl(sv, e + 0, 32), sB = __shfl(sv, e + 1, 32);
    int sC = __shfl(sv, e + 2, 32), sD = __shfl(sv, e + 3, 32);
    int sE = __shfl(sv, e + 4, 32), sF = __shfl(sv, e + 5, 32);
    int sG = __shfl(sv, e + 6, 32), sH = __shfl(sv, e + 7, 32);
    uint2 uA = hp[(size_t)sA * 32 + fl];
    uint2 uB = hp[(size_t)sB * 32 + fl];
    uint2 uC = hp[(size_t)sC * 32 + fl];
    uint2 uD = hp[(size_t)sD * 32 + fl];
    uint2 uE = hp[(size_t)sE * 32 + fl];
    uint2 uF = hp[(size_t)sF * 32 + fl];
    uint2 uG = hp[(size_t)sG * 32 + fl];
    uint2 uH = hp[(size_t)sH * 32 + fl];
    float2 lA = h2f(uA.x), hA = h2f(uA.y), lB = h2f(uB.x), hB = h2f(uB.y);
    float2 lC = h2f(uC.x), hC = h2f(uC.y), lD = h2f(uD.x), hD = h2f(uD.y);
    float2 lE = h2f(uE.x), hE = h2f(uE.y), lF = h2f(uF.x), hF = h2f(uF.y);
    float2 lG = h2f(uG.x), hG = h2f(uG.y), lH = h2f(uH.x), hH = h2f(uH.y);
    a0 += ((lA.x + lB.x) + (lC.x + lD.x)) + ((lE.x + lF.x) + (lG.x + lH.x));
    a1 += ((lA.y + lB.y) + (lC.y + lD.y)) + ((lE.y + lF.y) + (lG.y + lH.y));
    a2 += ((hA.x + hB.x) + (hC.x + hD.x)) + ((hE.x + hF.x) + (hG.x + hH.x));
    a3 += ((hA.y + hB.y) + (hC.y + hD.y)) + ((hE.y + hF.y) + (hG.y + hH.y));
  }
  for (; e < lim; ++e) {
    int s = __shfl(sv, e, 32);
    uint2 u = hp[(size_t)s * 32 + fl];
    float2 l = h2f(u.x), h = h2f(u.y);
    a0 += l.x; a1 += l.y; a2 += h.x; a3 += h.y;
  }
  for (int ee = beg + 32; ee < end; ++ee) {  // deg>32 fallback (rare, uniform)
    uint2 u = hp[(size_t)csr_src[ee] * 32 + fl];
    float2 l = h2f(u.x), h = h2f(u.y);
    a0 += l.x; a1 += l.y; a2 += h.x; a3 += h.y;
  }
  float di = dinv[node];
  float4 bb = *(const float4*)(b + 4 * fl);
  float o0 = fmaxf(fmaf(di, a0, bb.x), 0.f);
  float o1 = fmaxf(fmaf(di, a1, bb.y), 0.f);
  float o2 = fmaxf(fmaf(di, a2, bb.z), 0.f);
  float o3 = fmaxf(fmaf(di, a3, bb.w), 0.f);
  uint2 o;
  o.x = f2h(o0, o1);
  o.y = f2h(o2, o3);
  y[(size_t)node * 32 + fl] = o;
}

// ---- agg2: out[i](f32) = dinv_i*(h'_i + sum_src h'_src) + b2, 64 feats ----
// h' rows: 32 uints (fp16x2) = 128B, dinv-prescaled. One 32-lane segment/node.
__global__ __launch_bounds__(256) void agg2_k(const uint* __restrict__ hp,
                                              const float* __restrict__ dinv,
                                              const int* __restrict__ offsets,
                                              const int* __restrict__ csr_src,
                                              const float* __restrict__ b,
                                              float* __restrict__ out, int n) {
  int wv = threadIdx.x >> 6;
  int lane = threadIdx.x & 63;
  int half = lane >> 5;
  int fl = lane & 31;
  int node = blockIdx.x * 8 + wv * 2 + half;
  if (node >= n) return;
  int beg = offsets[node], end = offsets[node + 1];
  int deg = end - beg;
  float2 self = h2f(hp[(size_t)node * 32 + fl]);
  float ax = self.x, ay = self.y;
  int sv = 0;
  if (fl < deg) sv = csr_src[beg + fl];
  int lim = deg < 32 ? deg : 32;
  int e = 0;
  for (; e + 8 <= lim; e += 8) {
    int s0 = __shfl(sv, e + 0, 32), s1 = __shfl(sv, e + 1, 32);
    int s2 = __shfl(sv, e + 2, 32), s3 = __shfl(sv, e + 3, 32);
    int s4 = __shfl(sv, e + 4, 32), s5 = __shfl(sv, e + 5, 32);
    int s6 = __shfl(sv, e + 6, 32), s7 = __shfl(sv, e + 7, 32);
    uint u0 = hp[(size_t)s0 * 32 + fl];
    uint u1 = hp[(size_t)s1 * 32 + fl];
    uint u2 = hp[(size_t)s2 * 32 + fl];
    uint u3 = hp[(size_t)s3 * 32 + fl];
    uint u4 = hp[(size_t)s4 * 32 + fl];
    uint u5 = hp[(size_t)s5 * 32 + fl];
    uint u6 = hp[(size_t)s6 * 32 + fl];
    uint u7 = hp[(size_t)s7 * 32 + fl];
    float2 v0 = h2f(u0), v1 = h2f(u1), v2 = h2f(u2), v3 = h2f(u3);
    float2 v4 = h2f(u4), v5 = h2f(u5), v6 = h2f(u6), v7 = h2f(u7);
    ax += ((v0.x + v1.x) + (v2.x + v3.x)) + ((v4.x + v5.x) + (v6.x + v7.x));
    ay += ((v0.y + v1.y) + (v2.y + v3.y)) + ((v4.y + v5.y) + (v6.y + v7.y));
  }
  for (; e < lim; ++e) {
    int s = __shfl(sv, e, 32);
    float2 v = h2f(hp[(size_t)s * 32 + fl]);
    ax += v.x;
    ay += v.y;
  }
  for (int ee = beg + 32; ee < end; ++ee) {
    float2 v = h2f(hp[(size_t)csr_src[ee] * 32 + fl]);
    ax += v.x;
    ay += v.y;
  }
  float di = dinv[node];
  float2 bb = ((const float2*)b)[fl];
  float2 o;
  o.x = fmaf(di, ax, bb.x);
  o.y = fmaf(di, ay, bb.y);
  ((float2*)out)[(size_t)node * 32 + fl] = o;
}

extern "C" void kernel_launch(void* const* d_in, const int* in_sizes, int n_in,
                              void* d_out, int out_size, void* d_ws, size_t ws_size,
                              hipStream_t stream) {
  const float* x  = (const float*)d_in[0];
  const int*   ei = (const int*)d_in[1];
  const float* W1 = (const float*)d_in[2];
  const float* b1 = (const float*)d_in[3];
  const float* W2 = (const float*)d_in[4];
  const float* b2 = (const float*)d_in[5];
  float* out = (float*)d_out;

  const int N = in_sizes[0] / 128;   // 50000
  const int E = in_sizes[1] / 2;     // 800000
  const int NBUCK = (N + BSIZE - 1) >> BSHIFT;   // 391
  const int NCHUNK = (E + CHUNK - 1) / CHUNK;    // 196

  char* w = (char*)d_ws;
  size_t off = 0;
  auto alloc = [&](size_t bytes) -> void* {
    void* p = w + off;
    off = (off + bytes + 511) & ~(size_t)511;
    return p;
  };
  int*       gh      = (int*)alloc((size_t)NBUCK * NCHUNK * 4);
  int*       gbase   = (int*)alloc((size_t)NBUCK * NCHUNK * 4);
  int*       totals  = (int*)alloc((size_t)NBUCK * 4);
  int*       bstart  = (int*)alloc((size_t)(NBUCK + 1) * 4);
  int*       tmp     = (int*)alloc((size_t)E * 4);
  int*       offsets = (int*)alloc((size_t)(N + 1) * 4);
  float*     dinv    = (float*)alloc((size_t)N * 4);
  int*       csr     = (int*)alloc((size_t)E * 4);
  _Float16*  pW      = (_Float16*)alloc(24576 * 2);            // W1|W2 packs
  _Float16*  h1      = (_Float16*)alloc((size_t)N * 128 * 2);  // fp16, prescaled
  _Float16*  y       = (_Float16*)alloc((size_t)N * 128 * 2);  // fp16 (relu out)
  _Float16*  h2      = (_Float16*)alloc((size_t)N * 64 * 2);   // fp16, prescaled

  const int GB = (N + 63) / 64;   // 782
  const int AB = (N + 7) / 8;     // 6250 (8 nodes/block, 2 per wave)

  hipMemsetAsync(totals, 0, (size_t)NBUCK * 4, stream);
  hist_prep_k<<<NCHUNK + 96, 256, 0, stream>>>(ei, gh, totals, W1, W2, pW,
                                               E, NCHUNK, NBUCK);
  scanrow_k<<<NBUCK, 256, 0, stream>>>(gh, totals, gbase, bstart, offsets,
                                       NCHUNK, NBUCK, N, E);
  part_k<<<NCHUNK, 256, 0, stream>>>(ei, gbase, tmp, E, NCHUNK, NBUCK);
  bucket_k<<<NBUCK, 256, 0, stream>>>(tmp, bstart, csr, offsets, dinv, N);

  mfma_gemm_k<128, false><<<GB, 256, 0, stream>>>(x, pW, dinv, h1, N);
  agg1_k<<<AB, 256, 0, stream>>>((const uint2*)h1, dinv, offsets, csr, b1,
                                 (uint2*)y, N);
  mfma_gemm_k<64, true><<<GB, 256, 0, stream>>>(y, pW + 16384, dinv, h2, N);
  agg2_k<<<AB, 256, 0, stream>>>((const uint*)h2, dinv, offsets, csr, b2, out, N);
}

// Round 17
// 105.606 us; speedup vs baseline: 7.2101x; 1.0767x over previous
//
#include <hip/hip_runtime.h>
#include <hip/hip_bf16.h>
#include <hip/hip_fp16.h>

// GCN 2-layer: N=50000 nodes, E=800000 edges, 128->128(relu)->64.
// CSR build: two-level LDS-binned partition (128-node buckets, no global
// atomics). GEMMs: fp16 MFMA 16x16x32, LDS-free, prepacked W.
// agg1: 32-lane segment per node, uint2 lanes (256B/row), width-32 shuffles.
// agg2: 32-lane segment per node, uint lanes (128B/row). f32 accumulation.
// (Round-11 champion configuration, restored verbatim.)

#define CHUNK 4096   // edges per partition chunk
#define BSHIFT 7
#define BSIZE 128    // nodes per bucket
#define BCAP 4096    // max edges per bucket held in LDS (avg ~2046)

typedef unsigned int uint;
typedef _Float16 f16x8 __attribute__((ext_vector_type(8)));
typedef float f32x4 __attribute__((ext_vector_type(4)));

__device__ __forceinline__ float2 h2f(uint v) {
  __half2 h;
  __builtin_memcpy(&h, &v, 4);
  return __half22float2(h);
}

__device__ __forceinline__ uint f2h(float a, float b) {
  __half2 h = __halves2half2(__float2half_rn(a), __float2half_rn(b));
  uint r;
  __builtin_memcpy(&r, &h, 4);
  return r;
}

// int64-vs-int32 detection per block: wave-0 ballot over first 64 high words.
__device__ __forceinline__ int block_is64(const int* ei, int* s_is64) {
  if (threadIdx.x < 64) {
    unsigned long long m = __ballot(ei[2 * threadIdx.x + 1] != 0);
    if (threadIdx.x == 0) *s_is64 = (m == 0ULL) ? 1 : 0;
  }
  __syncthreads();
  return *s_is64;
}

// A1 (+fused W-prep): blocks < nchunk do per-chunk histogram over buckets
// (dst>>BSHIFT); blocks >= nchunk pack W1/W2 into fragment-linear fp16.
__global__ __launch_bounds__(256) void hist_prep_k(const int* __restrict__ ei,
                                                   int* __restrict__ gh,
                                                   const float* __restrict__ W1,
                                                   const float* __restrict__ W2,
                                                   _Float16* __restrict__ P,
                                                   int E, int nchunk, int nbuck) {
  if (blockIdx.x >= nchunk) {
    int li = (blockIdx.x - nchunk) * 256 + threadIdx.x;  // 0..24575
    if (li >= 24576) return;
    const float* W;
    _Float16* dst;
    int NC, idx;
    if (li < 16384) { W = W1; dst = P;         NC = 128; idx = li; }
    else            { W = W2; dst = P + 16384; NC = 64;  idx = li - 16384; }
    int NF = NC >> 4;
    int j = idx & 7;
    int l = (idx >> 3) & 63;
    int rest = idx >> 9;
    int c = rest % NF;
    int t = rest / NF;
    int k = t * 32 + ((l >> 4) << 3) + j;
    int col = c * 16 + (l & 15);
    dst[idx] = (_Float16)W[(size_t)k * NC + col];
    return;
  }
  __shared__ int h[512];
  __shared__ int s_is64;
  int c = blockIdx.x;
  for (int i = threadIdx.x; i < 512; i += 256) h[i] = 0;
  int is64 = block_is64(ei, &s_is64);  // includes __syncthreads
  int base = c * CHUNK;
  int lim = min(CHUNK, E - base);
  for (int i = threadIdx.x; i < lim; i += 256) {
    int e = base + i;
    int d = is64 ? ei[2 * ((size_t)E + e)] : ei[(size_t)E + e];
    atomicAdd(&h[d >> BSHIFT], 1);
  }
  __syncthreads();
  for (int k = threadIdx.x; k < nbuck; k += 256) gh[k * nchunk + c] = h[k];
}

// A2a: per-bucket totals (block k sums its gh row)
__global__ __launch_bounds__(256) void tot_k(const int* __restrict__ gh,
                                             int* __restrict__ totals, int nchunk) {
  __shared__ int sd[256];
  int k = blockIdx.x;
  int s = 0;
  for (int i = threadIdx.x; i < nchunk; i += 256) s += gh[k * nchunk + i];
  sd[threadIdx.x] = s;
  __syncthreads();
  for (int o = 128; o > 0; o >>= 1) {
    if (threadIdx.x < o) sd[threadIdx.x] += sd[threadIdx.x + o];
    __syncthreads();
  }
  if (threadIdx.x == 0) totals[k] = sd[0];
}

// A2b: block k: bucketStart[k] (= sum totals[<k]) + scan of row k -> gbase.
__global__ __launch_bounds__(256) void scanrow_k(const int* __restrict__ gh,
                                                 const int* __restrict__ totals,
                                                 int* __restrict__ gbase,
                                                 int* __restrict__ bucketStart,
                                                 int* __restrict__ offsets,
                                                 int nchunk, int nbuck, int N, int E) {
  __shared__ int st[256];
  int k = blockIdx.x;
  int t = threadIdx.x;
  int partial = 0;
  for (int i = t; i < k; i += 256) partial += totals[i];
  st[t] = partial;
  __syncthreads();
  for (int o = 128; o > 0; o >>= 1) {
    if (t < o) st[t] += st[t + o];
    __syncthreads();
  }
  int bs = st[0];
  if (t == 0) {
    bucketStart[k] = bs;
    if (k == nbuck - 1) { bucketStart[nbuck] = E; offsets[N] = E; }
  }
  __syncthreads();
  int x = (t < nchunk) ? gh[k * nchunk + t] : 0;
  st[t] = x;
  __syncthreads();
  int incl = x;
  for (int o = 1; o < 256; o <<= 1) {
    int add = (t >= o) ? st[t - o] : 0;
    __syncthreads();
    incl += add;
    st[t] = incl;
    __syncthreads();
  }
  if (t < nchunk) gbase[k * nchunk + t] = bs + (incl - x);
}

// A3: partition edges into bucket-grouped tmp, packed (src16 | dstlow7<<16)
__global__ __launch_bounds__(256) void part_k(const int* __restrict__ ei,
                                              const int* __restrict__ gbase,
                                              int* __restrict__ tmp,
                                              int E, int nchunk, int nbuck) {
  __shared__ int cur[512];
  __shared__ int s_is64;
  int c = blockIdx.x;
  for (int i = threadIdx.x; i < nbuck; i += 256) cur[i] = gbase[i * nchunk + c];
  int is64 = block_is64(ei, &s_is64);
  int base = c * CHUNK;
  int lim = min(CHUNK, E - base);
  for (int i = threadIdx.x; i < lim; i += 256) {
    int e = base + i;
    int s, d;
    if (is64) {
      s = ei[2 * (size_t)e];
      d = ei[2 * ((size_t)E + e)];
    } else {
      s = ei[e];
      d = ei[(size_t)E + e];
    }
    int p = atomicAdd(&cur[d >> BSHIFT], 1);
    tmp[p] = s | ((d & (BSIZE - 1)) << 16);
  }
}

// B: one block per 128-node bucket: LDS count+scan -> offsets, dinv, csr_src
__global__ __launch_bounds__(256) void bucket_k(const int* __restrict__ tmp,
                                                const int* __restrict__ bucketStart,
                                                int* __restrict__ csr_src,
                                                int* __restrict__ offsets,
                                                float* __restrict__ dinv,
                                                int N) {
  __shared__ int ebuf[BCAP];
  __shared__ int cnt[BSIZE];
  __shared__ int st[256];
  __shared__ int lofs[BSIZE];
  int k = blockIdx.x;
  int b0 = bucketStart[k], b1 = bucketStart[k + 1];
  int sz = b1 - b0;
  int t = threadIdx.x;
  if (t < BSIZE) cnt[t] = 0;
  __syncthreads();
  bool inlds = (sz <= BCAP);
  if (inlds) {
    for (int i = t; i < sz; i += 256) {
      int v = tmp[b0 + i];
      ebuf[i] = v;
      atomicAdd(&cnt[v >> 16], 1);
    }
  } else {
    for (int i = t; i < sz; i += 256) atomicAdd(&cnt[tmp[b0 + i] >> 16], 1);
  }
  __syncthreads();
  int x = (t < BSIZE) ? cnt[t] : 0;
  st[t] = x;
  __syncthreads();
  int incl = x;
  for (int o = 1; o < 256; o <<= 1) {
    int add = (t >= o) ? st[t - o] : 0;
    __syncthreads();
    incl += add;
    st[t] = incl;
    __syncthreads();
  }
  int node = (k << BSHIFT) + t;
  if (t < BSIZE) {
    lofs[t] = incl - x;
    if (node < N) {
      offsets[node] = b0 + lofs[t];
      dinv[node] = rsqrtf((float)(x + 1));  // +1 self-loop
    }
  }
  __syncthreads();
  if (t < BSIZE) cnt[t] = lofs[t];  // reuse as cursor
  __syncthreads();
  if (inlds) {
    for (int i = t; i < sz; i += 256) {
      int v = ebuf[i];
      int p = atomicAdd(&cnt[v >> 16], 1);
      csr_src[b0 + p] = v & 0xFFFF;
    }
  } else {
    for (int i = t; i < sz; i += 256) {
      int v = tmp[b0 + i];
      int p = atomicAdd(&cnt[v >> 16], 1);
      csr_src[b0 + p] = v & 0xFFFF;
    }
  }
}

// ---- MFMA GEMM: H(fp16 row-major) = dinv[row] * (X[M,128] @ W[128,NC]) ----
// 4 waves/block, wave w: rows blk*64 + w*16. No LDS.
template <int NC, bool A16>
__global__ __launch_bounds__(256) void mfma_gemm_k(const void* __restrict__ Xv,
                                                   const _Float16* __restrict__ Wp,
                                                   const float* __restrict__ dinv,
                                                   _Float16* __restrict__ H, int M) {
  constexpr int NF = NC / 16;
  int lane = threadIdx.x & 63;
  int w = threadIdx.x >> 6;
  int row0 = blockIdx.x * 64 + w * 16;
  int arow = row0 + (lane & 15);
  bool av = arow < M;
  const uint4* wp = (const uint4*)Wp;

  f32x4 acc[NF];
#pragma unroll
  for (int c = 0; c < NF; ++c) acc[c] = (f32x4){0.f, 0.f, 0.f, 0.f};

#pragma unroll
  for (int t = 0; t < 4; ++t) {
    f16x8 a;
    if constexpr (A16) {
      const _Float16* xr = (const _Float16*)Xv + (size_t)arow * 128 + ((lane >> 4) << 3);
      uint4 araw = av ? *(const uint4*)(xr + t * 32) : make_uint4(0u, 0u, 0u, 0u);
      __builtin_memcpy(&a, &araw, 16);
    } else {
      const float* xr = (const float*)Xv + (size_t)arow * 128 + ((lane >> 4) << 3);
      float4 lo = av ? *(const float4*)(xr + t * 32) : make_float4(0.f, 0.f, 0.f, 0.f);
      float4 hi = av ? *(const float4*)(xr + t * 32 + 4) : make_float4(0.f, 0.f, 0.f, 0.f);
      a[0] = (_Float16)lo.x; a[1] = (_Float16)lo.y;
      a[2] = (_Float16)lo.z; a[3] = (_Float16)lo.w;
      a[4] = (_Float16)hi.x; a[5] = (_Float16)hi.y;
      a[6] = (_Float16)hi.z; a[7] = (_Float16)hi.w;
    }
#pragma unroll
    for (int c = 0; c < NF; ++c) {
      uint4 braw = wp[(t * NF + c) * 64 + lane];
      f16x8 b;
      __builtin_memcpy(&b, &braw, 16);
      acc[c] = __builtin_amdgcn_mfma_f32_16x16x32_f16(a, b, acc[c], 0, 0, 0);
    }
  }

  int rbase = row0 + ((lane >> 4) << 2);
#pragma unroll
  for (int r = 0; r < 4; ++r) {
    int row = rbase + r;
    if (row < M) {
      float di = dinv[row];
#pragma unroll
      for (int c = 0; c < NF; ++c)
        H[(size_t)row * NC + c * 16 + (lane & 15)] = (_Float16)(di * acc[c][r]);
    }
  }
}

// ---- agg1: y[i](fp16) = relu( dinv_i*(h'_i + sum_src h'_src) + b1 ), 128 f ----
// h' rows: 32 uint2 (fp16x4) = 256B. One 32-lane SEGMENT per node (2/wave):
// trip counts segment-uniform; shuffles width-32. Lane fl holds feats 4fl..4fl+3.
__global__ __launch_bounds__(256) void agg1_k(const uint2* __restrict__ hp,
                                              const float* __restrict__ dinv,
                                              const int* __restrict__ offsets,
                                              const int* __restrict__ csr_src,
                                              const float* __restrict__ b,
                                              uint2* __restrict__ y, int n) {
  int wv = threadIdx.x >> 6;
  int lane = threadIdx.x & 63;
  int half = lane >> 5;
  int fl = lane & 31;
  int node = blockIdx.x * 8 + wv * 2 + half;
  if (node >= n) return;  // uniform within segment
  int beg = offsets[node], end = offsets[node + 1];
  int deg = end - beg;
  uint2 su = hp[(size_t)node * 32 + fl];
  float2 sl = h2f(su.x), sh = h2f(su.y);
  float a0 = sl.x, a1 = sl.y, a2 = sh.x, a3 = sh.y;
  int sv = 0;
  if (fl < deg) sv = csr_src[beg + fl];
  int lim = deg < 32 ? deg : 32;
  int e = 0;
  for (; e + 8 <= lim; e += 8) {
    int sA = __shfl(sv, e + 0, 32), sB = __shfl(sv, e + 1, 32);
    int sC = __shfl(sv, e + 2, 32), sD = __shfl(sv, e + 3, 32);
    int sE = __shfl(sv, e + 4, 32), sF = __shfl(sv, e + 5, 32);
    int sG = __shfl(sv, e + 6, 32), sH = __shfl(sv, e + 7, 32);
    uint2 uA = hp[(size_t)sA * 32 + fl];
    uint2 uB = hp[(size_t)sB * 32 + fl];
    uint2 uC = hp[(size_t)sC * 32 + fl];
    uint2 uD = hp[(size_t)sD * 32 + fl];
    uint2 uE = hp[(size_t)sE * 32 + fl];
    uint2 uF = hp[(size_t)sF * 32 + fl];
    uint2 uG = hp[(size_t)sG * 32 + fl];
    uint2 uH = hp[(size_t)sH * 32 + fl];
    float2 lA = h2f(uA.x), hA = h2f(uA.y), lB = h2f(uB.x), hB = h2f(uB.y);
    float2 lC = h2f(uC.x), hC = h2f(uC.y), lD = h2f(uD.x), hD = h2f(uD.y);
    float2 lE = h2f(uE.x), hE = h2f(uE.y), lF = h2f(uF.x), hF = h2f(uF.y);
    float2 lG = h2f(uG.x), hG = h2f(uG.y), lH = h2f(uH.x), hH = h2f(uH.y);
    a0 += ((lA.x + lB.x) + (lC.x + lD.x)) + ((lE.x + lF.x) + (lG.x + lH.x));
    a1 += ((lA.y + lB.y) + (lC.y + lD.y)) + ((lE.y + lF.y) + (lG.y + lH.y));
    a2 += ((hA.x + hB.x) + (hC.x + hD.x)) + ((hE.x + hF.x) + (hG.x + hH.x));
    a3 += ((hA.y + hB.y) + (hC.y + hD.y)) + ((hE.y + hF.y) + (hG.y + hH.y));
  }
  for (; e < lim; ++e) {
    int s = __shfl(sv, e, 32);
    uint2 u = hp[(size_t)s * 32 + fl];
    float2 l = h2f(u.x), h = h2f(u.y);
    a0 += l.x; a1 += l.y; a2 += h.x; a3 += h.y;
  }
  for (int ee = beg + 32; ee < end; ++ee) {  // deg>32 fallback (rare, uniform)
    uint2 u = hp[(size_t)csr_src[ee] * 32 + fl];
    float2 l = h2f(u.x), h = h2f(u.y);
    a0 += l.x; a1 += l.y; a2 += h.x; a3 += h.y;
  }
  float di = dinv[node];
  float4 bb = *(const float4*)(b + 4 * fl);
  float o0 = fmaxf(fmaf(di, a0, bb.x), 0.f);
  float o1 = fmaxf(fmaf(di, a1, bb.y), 0.f);
  float o2 = fmaxf(fmaf(di, a2, bb.z), 0.f);
  float o3 = fmaxf(fmaf(di, a3, bb.w), 0.f);
  uint2 o;
  o.x = f2h(o0, o1);
  o.y = f2h(o2, o3);
  y[(size_t)node * 32 + fl] = o;
}

// ---- agg2: out[i](f32) = dinv_i*(h'_i + sum_src h'_src) + b2, 64 feats ----
// h' rows: 32 uints (fp16x2) = 128B. One 32-lane segment per node.
__global__ __launch_bounds__(256) void agg2_k(const uint* __restrict__ hp,
                                              const float* __restrict__ dinv,
                                              const int* __restrict__ offsets,
                                              const int* __restrict__ csr_src,
                                              const float* __restrict__ b,
                                              float* __restrict__ out, int n) {
  int wv = threadIdx.x >> 6;
  int lane = threadIdx.x & 63;
  int half = lane >> 5;
  int fl = lane & 31;
  int node = blockIdx.x * 8 + wv * 2 + half;
  if (node >= n) return;
  int beg = offsets[node], end = offsets[node + 1];
  int deg = end - beg;
  float2 self = h2f(hp[(size_t)node * 32 + fl]);
  float ax = self.x, ay = self.y;
  int sv = 0;
  if (fl < deg) sv = csr_src[beg + fl];
  int lim = deg < 32 ? deg : 32;
  int e = 0;
  for (; e + 8 <= lim; e += 8) {
    int s0 = __shfl(sv, e + 0, 32), s1 = __shfl(sv, e + 1, 32);
    int s2 = __shfl(sv, e + 2, 32), s3 = __shfl(sv, e + 3, 32);
    int s4 = __shfl(sv, e + 4, 32), s5 = __shfl(sv, e + 5, 32);
    int s6 = __shfl(sv, e + 6, 32), s7 = __shfl(sv, e + 7, 32);
    uint u0 = hp[(size_t)s0 * 32 + fl];
    uint u1 = hp[(size_t)s1 * 32 + fl];
    uint u2 = hp[(size_t)s2 * 32 + fl];
    uint u3 = hp[(size_t)s3 * 32 + fl];
    uint u4 = hp[(size_t)s4 * 32 + fl];
    uint u5 = hp[(size_t)s5 * 32 + fl];
    uint u6 = hp[(size_t)s6 * 32 + fl];
    uint u7 = hp[(size_t)s7 * 32 + fl];
    float2 v0 = h2f(u0), v1 = h2f(u1), v2 = h2f(u2), v3 = h2f(u3);
    float2 v4 = h2f(u4), v5 = h2f(u5), v6 = h2f(u6), v7 = h2f(u7);
    ax += ((v0.x + v1.x) + (v2.x + v3.x)) + ((v4.x + v5.x) + (v6.x + v7.x));
    ay += ((v0.y + v1.y) + (v2.y + v3.y)) + ((v4.y + v5.y) + (v6.y + v7.y));
  }
  for (; e < lim; ++e) {
    int s = __shfl(sv, e, 32);
    float2 v = h2f(hp[(size_t)s * 32 + fl]);
    ax += v.x;
    ay += v.y;
  }
  for (int ee = beg + 32; ee < end; ++ee) {
    float2 v = h2f(hp[(size_t)csr_src[ee] * 32 + fl]);
    ax += v.x;
    ay += v.y;
  }
  float di = dinv[node];
  float2 bb = ((const float2*)b)[fl];
  float2 o;
  o.x = fmaf(di, ax, bb.x);
  o.y = fmaf(di, ay, bb.y);
  ((float2*)out)[(size_t)node * 32 + fl] = o;
}

extern "C" void kernel_launch(void* const* d_in, const int* in_sizes, int n_in,
                              void* d_out, int out_size, void* d_ws, size_t ws_size,
                              hipStream_t stream) {
  const float* x  = (const float*)d_in[0];
  const int*   ei = (const int*)d_in[1];
  const float* W1 = (const float*)d_in[2];
  const float* b1 = (const float*)d_in[3];
  const float* W2 = (const float*)d_in[4];
  const float* b2 = (const float*)d_in[5];
  float* out = (float*)d_out;

  const int N = in_sizes[0] / 128;   // 50000
  const int E = in_sizes[1] / 2;     // 800000
  const int NBUCK = (N + BSIZE - 1) >> BSHIFT;   // 391
  const int NCHUNK = (E + CHUNK - 1) / CHUNK;    // 196

  char* w = (char*)d_ws;
  size_t off = 0;
  auto alloc = [&](size_t bytes) -> void* {
    void* p = w + off;
    off = (off + bytes + 511) & ~(size_t)511;
    return p;
  };
  int*       gh      = (int*)alloc((size_t)NBUCK * NCHUNK * 4);
  int*       gbase   = (int*)alloc((size_t)NBUCK * NCHUNK * 4);
  int*       totals  = (int*)alloc((size_t)NBUCK * 4);
  int*       bstart  = (int*)alloc((size_t)(NBUCK + 1) * 4);
  int*       tmp     = (int*)alloc((size_t)E * 4);
  int*       offsets = (int*)alloc((size_t)(N + 1) * 4);
  float*     dinv    = (float*)alloc((size_t)N * 4);
  int*       csr_src = (int*)alloc((size_t)E * 4);
  _Float16*  pW      = (_Float16*)alloc(24576 * 2);            // W1|W2 packs
  _Float16*  h1      = (_Float16*)alloc((size_t)N * 128 * 2);  // fp16 row-major
  _Float16*  y       = (_Float16*)alloc((size_t)N * 128 * 2);  // fp16 row-major
  _Float16*  h2      = (_Float16*)alloc((size_t)N * 64 * 2);   // fp16 row-major

  const int GB  = (N + 63) / 64;
  const int AB  = (N + 7) / 8;   // 8 nodes per block (2 per wave)

  hist_prep_k<<<NCHUNK + 96, 256, 0, stream>>>(ei, gh, W1, W2, pW, E, NCHUNK, NBUCK);
  tot_k<<<NBUCK, 256, 0, stream>>>(gh, totals, NCHUNK);
  scanrow_k<<<NBUCK, 256, 0, stream>>>(gh, totals, gbase, bstart, offsets,
                                       NCHUNK, NBUCK, N, E);
  part_k<<<NCHUNK, 256, 0, stream>>>(ei, gbase, tmp, E, NCHUNK, NBUCK);
  bucket_k<<<NBUCK, 256, 0, stream>>>(tmp, bstart, csr_src, offsets, dinv, N);

  mfma_gemm_k<128, false><<<GB, 256, 0, stream>>>(x, pW, dinv, h1, N);
  agg1_k<<<AB, 256, 0, stream>>>((const uint2*)h1, dinv, offsets, csr_src, b1,
                                 (uint2*)y, N);
  mfma_gemm_k<64, true><<<GB, 256, 0, stream>>>(y, pW + 16384, dinv, h2, N);
  agg2_k<<<AB, 256, 0, stream>>>((const uint*)h2, dinv, offsets, csr_src, b2, out, N);
}